// Round 5
// baseline (281.333 us; speedup 1.0000x reference)
//
#include <hip/hip_runtime.h>
#include <hip/hip_bf16.h>

#define N_NODES_C 100000
#define NSCAN     102400      // N padded to 25 * 4096 for the scan
#define SCAN_BS   1024        // threads per scan block (4 elems each -> 4096/block)
#define NB_SCAN   (NSCAN / (SCAN_BS * 4))   // 25 blocks

// ---------------------------------------------------------------------------
// bf16 helpers (packed 2 per uint, little-endian: low ushort = even element)
// ---------------------------------------------------------------------------
__device__ __forceinline__ float bflo(unsigned u) { return __uint_as_float(u << 16); }
__device__ __forceinline__ float bfhi(unsigned u) { return __uint_as_float(u & 0xffff0000u); }
__device__ __forceinline__ unsigned pack2(float f0, float f1)
{
    unsigned u0 = __float_as_uint(f0); u0 = (u0 + 0x7fffu + ((u0 >> 16) & 1u)) >> 16;
    unsigned u1 = __float_as_uint(f1); u1 = (u1 + 0x7fffu + ((u1 >> 16) & 1u)) >> 16;
    return u0 | (u1 << 16);
}

// h_src f32 -> packed bf16 copy (8 floats per thread)
__global__ __launch_bounds__(256) void convert_bf16(
    const float* __restrict__ x, uint4* __restrict__ y, int n8)
{
    int i = blockIdx.x * 256 + threadIdx.x;
    if (i >= n8) return;
    const float4* x4 = reinterpret_cast<const float4*>(x);
    float4 a = x4[i * 2 + 0];
    float4 b = x4[i * 2 + 1];
    uint4 o;
    o.x = pack2(a.x, a.y);
    o.y = pack2(a.z, a.w);
    o.z = pack2(b.x, b.y);
    o.w = pack2(b.z, b.w);
    y[i] = o;
}

// ---------------------------------------------------------------------------
// CSR build: histogram(+rank) -> block scan -> scan_add(inline partials) -> fill
// ---------------------------------------------------------------------------
__global__ __launch_bounds__(256) void edge_hist(
    const int* __restrict__ dst, int* __restrict__ counts,
    int* __restrict__ rank, int n_edges)
{
    int i = blockIdx.x * 256 + threadIdx.x;
    int b4 = i * 4;
    if (b4 + 3 < n_edges) {
        int4 d = reinterpret_cast<const int4*>(dst)[i];
        int4 rk;
        rk.x = atomicAdd(&counts[d.x], 1);
        rk.y = atomicAdd(&counts[d.y], 1);
        rk.z = atomicAdd(&counts[d.z], 1);
        rk.w = atomicAdd(&counts[d.w], 1);
        reinterpret_cast<int4*>(rank)[i] = rk;
    } else {
        for (int e = b4; e < n_edges; ++e)
            rank[e] = atomicAdd(&counts[dst[e]], 1);
    }
}

__global__ __launch_bounds__(SCAN_BS) void scan_block(
    const int* __restrict__ counts, int* __restrict__ offsets,
    int* __restrict__ partials)
{
    __shared__ int sd[2][SCAN_BS];
    int t = threadIdx.x, b = blockIdx.x;
    int4 c = reinterpret_cast<const int4*>(counts)[b * SCAN_BS + t];
    int tot = c.x + c.y + c.z + c.w;
    sd[0][t] = tot;
    __syncthreads();
    int pin = 0;
    #pragma unroll
    for (int off = 1; off < SCAN_BS; off <<= 1) {
        int v = sd[pin][t];
        if (t >= off) v += sd[pin][t - off];
        sd[pin ^ 1][t] = v;
        pin ^= 1;
        __syncthreads();
    }
    int incl = sd[pin][t];      // inclusive scan of per-thread sums
    int excl = incl - tot;
    int4 o;
    o.x = excl;
    o.y = excl + c.x;
    o.z = excl + c.x + c.y;
    o.w = excl + c.x + c.y + c.z;
    reinterpret_cast<int4*>(offsets)[b * SCAN_BS + t] = o;
    if (t == SCAN_BS - 1) partials[b] = incl;
}

// one block per scan_block tile; thread 0 sums the (<=24) preceding partials
__global__ __launch_bounds__(SCAN_BS) void scan_add(
    int* __restrict__ offsets, const int* __restrict__ partials)
{
    __shared__ int base_s;
    int b = blockIdx.x;
    if (threadIdx.x == 0) {
        int s = 0;
        for (int i = 0; i < b; ++i) s += partials[i];
        base_s = s;
    }
    __syncthreads();
    int i = b * SCAN_BS + threadIdx.x;
    int4 v = reinterpret_cast<int4*>(offsets)[i];
    v.x += base_s; v.y += base_s; v.z += base_s; v.w += base_s;
    reinterpret_cast<int4*>(offsets)[i] = v;
}

__global__ __launch_bounds__(256) void edge_fill(
    const int* __restrict__ src, const int* __restrict__ dst,
    const int* __restrict__ rank, const int* __restrict__ offsets,
    int* __restrict__ edge_src, int n_edges)
{
    int i = blockIdx.x * 256 + threadIdx.x;
    int b4 = i * 4;
    if (b4 + 3 < n_edges) {
        int4 s  = reinterpret_cast<const int4*>(src)[i];
        int4 d  = reinterpret_cast<const int4*>(dst)[i];
        int4 rk = reinterpret_cast<const int4*>(rank)[i];
        edge_src[offsets[d.x] + rk.x] = s.x;
        edge_src[offsets[d.y] + rk.y] = s.y;
        edge_src[offsets[d.z] + rk.z] = s.z;
        edge_src[offsets[d.w] + rk.w] = s.w;
    } else {
        for (int e = b4; e < n_edges; ++e)
            edge_src[offsets[dst[e]] + rank[e]] = src[e];
    }
}

// ---------------------------------------------------------------------------
// Fused gather-mean + GEMM.
// Block: 256 threads, 32 nodes. LDS: X tile only (16KB, swizzled float4).
// Gather: 8 threads/node, each owns 8 bf16 features (one uint4 load/edge),
// 4-edge unroll -> 4 independent 16B loads in flight per lane; f32 accum.
// W streams from global in the GEMM loop (L1-resident, 4-lane dedup).
// ---------------------------------------------------------------------------
__global__ __launch_bounds__(256) void sage_fused(
    const uint4* __restrict__ hsb,      // packed bf16 h_src [N][8] uint4
    const float* __restrict__ h_dst,
    const int*   __restrict__ offsets,
    const int*   __restrict__ edge_src,
    const float* __restrict__ weight,   // [64][128] row-major
    const float* __restrict__ bias,     // [64]
    float*       __restrict__ out,      // [N][64]
    int n_nodes)
{
    __shared__ float4 x4[32 * 32];   // x4[r][k4] at r*32 + ((k4 + r) & 31)

    const int t    = threadIdx.x;
    const int base = blockIdx.x * 32;

    // stage h_dst (cols 0..15): 2 float4 per thread
    #pragma unroll
    for (int q = 0; q < 2; ++q) {
        int idx = t + q * 256;        // 0..511
        int r   = idx >> 4;
        int k4  = idx & 15;
        int g   = base + r;
        float4 xv = make_float4(0.f, 0.f, 0.f, 0.f);
        if (g < n_nodes)
            xv = reinterpret_cast<const float4*>(h_dst)[(size_t)g * 16 + k4];
        x4[r * 32 + ((k4 + r) & 31)] = xv;
    }

    // gather neighbor mean (cols 16..31): 8 threads/node, 4-edge unroll
    {
        const int j = t & 7;          // uint4 column (8 bf16 features)
        const int r = t >> 3;         // node within tile (0..31)
        const int g = base + r;
        float a0 = 0.f, a1 = 0.f, a2 = 0.f, a3 = 0.f;
        float a4 = 0.f, a5 = 0.f, a6 = 0.f, a7 = 0.f;
        float invd = 0.f;
        if (g < n_nodes) {
            int e0 = offsets[g];
            int e1 = offsets[g + 1];
            int e  = e0;
            for (; e + 4 <= e1; e += 4) {
                int s0 = edge_src[e + 0];
                int s1 = edge_src[e + 1];
                int s2 = edge_src[e + 2];
                int s3 = edge_src[e + 3];
                uint4 v0 = hsb[(size_t)s0 * 8 + j];
                uint4 v1 = hsb[(size_t)s1 * 8 + j];
                uint4 v2 = hsb[(size_t)s2 * 8 + j];
                uint4 v3 = hsb[(size_t)s3 * 8 + j];
                a0 += (bflo(v0.x) + bflo(v1.x)) + (bflo(v2.x) + bflo(v3.x));
                a1 += (bfhi(v0.x) + bfhi(v1.x)) + (bfhi(v2.x) + bfhi(v3.x));
                a2 += (bflo(v0.y) + bflo(v1.y)) + (bflo(v2.y) + bflo(v3.y));
                a3 += (bfhi(v0.y) + bfhi(v1.y)) + (bfhi(v2.y) + bfhi(v3.y));
                a4 += (bflo(v0.z) + bflo(v1.z)) + (bflo(v2.z) + bflo(v3.z));
                a5 += (bfhi(v0.z) + bfhi(v1.z)) + (bfhi(v2.z) + bfhi(v3.z));
                a6 += (bflo(v0.w) + bflo(v1.w)) + (bflo(v2.w) + bflo(v3.w));
                a7 += (bfhi(v0.w) + bfhi(v1.w)) + (bfhi(v2.w) + bfhi(v3.w));
            }
            for (; e < e1; ++e) {
                int s = edge_src[e];
                uint4 v = hsb[(size_t)s * 8 + j];
                a0 += bflo(v.x); a1 += bfhi(v.x);
                a2 += bflo(v.y); a3 += bfhi(v.y);
                a4 += bflo(v.z); a5 += bfhi(v.z);
                a6 += bflo(v.w); a7 += bfhi(v.w);
            }
            int degv = e1 - e0;
            invd = 1.0f / (float)(degv > 1 ? degv : 1);
        }
        // features 8j..8j+7  ->  float4 cols 16+2j, 17+2j
        float4 lo = make_float4(a0 * invd, a1 * invd, a2 * invd, a3 * invd);
        float4 hi = make_float4(a4 * invd, a5 * invd, a6 * invd, a7 * invd);
        x4[r * 32 + (((16 + 2 * j) + r) & 31)] = lo;
        x4[r * 32 + (((17 + 2 * j) + r) & 31)] = hi;
    }
    __syncthreads();

    // GEMM: thread tile = 2 nodes x 4 outs; W streamed from global (L1)
    const int m  = t & 15;    // out-group: o0 = 4m
    const int r0 = t >> 4;    // node base: rows r0, r0+16
    const int o0 = m * 4;

    const float4* w4g = reinterpret_cast<const float4*>(weight);
    float4 bv = reinterpret_cast<const float4*>(bias)[m];

    float acc[2][4];
    #pragma unroll
    for (int i = 0; i < 2; ++i) {
        acc[i][0] = bv.x; acc[i][1] = bv.y; acc[i][2] = bv.z; acc[i][3] = bv.w;
    }

    #pragma unroll 4
    for (int k4 = 0; k4 < 32; ++k4) {
        float4 wv[4];
        #pragma unroll
        for (int jj = 0; jj < 4; ++jj)
            wv[jj] = w4g[(o0 + jj) * 32 + k4];
        #pragma unroll
        for (int i = 0; i < 2; ++i) {
            int r = r0 + 16 * i;
            float4 xv = x4[r * 32 + ((k4 + r) & 31)];
            #pragma unroll
            for (int jj = 0; jj < 4; ++jj) {
                acc[i][jj] += xv.x * wv[jj].x + xv.y * wv[jj].y
                            + xv.z * wv[jj].z + xv.w * wv[jj].w;
            }
        }
    }

    #pragma unroll
    for (int i = 0; i < 2; ++i) {
        int g = base + r0 + 16 * i;
        if (g < n_nodes) {
            float4 ov = make_float4(acc[i][0], acc[i][1], acc[i][2], acc[i][3]);
            reinterpret_cast<float4*>(out)[(size_t)g * 16 + m] = ov;
        }
    }
}

// ---------------------------------------------------------------------------
extern "C" void kernel_launch(void* const* d_in, const int* in_sizes, int n_in,
                              void* d_out, int out_size, void* d_ws, size_t ws_size,
                              hipStream_t stream)
{
    const float* h_src  = (const float*)d_in[0];
    const float* h_dst  = (const float*)d_in[1];
    const int*   src    = (const int*)d_in[2];
    const int*   dst    = (const int*)d_in[3];
    const float* weight = (const float*)d_in[4];
    const float* bias   = (const float*)d_in[5];
    float*       out    = (float*)d_out;

    const int n_edges = in_sizes[2];
    const int n_feat  = in_sizes[0];   // N*64 floats

    // workspace layout (ints); all vector bases 16B-aligned
    int*   counts   = (int*)d_ws;              // NSCAN
    int*   offsets  = counts   + NSCAN;        // NSCAN  (offsets[N] valid)
    int*   partials = offsets  + NSCAN;        // 64
    int*   rank     = partials + 64;           // n_edges
    int*   edge_src = rank     + n_edges;      // n_edges
    uint4* hsb      = (uint4*)(edge_src + n_edges);   // N*64 bf16 = N*8 uint4

    // zero the histogram (ws is poisoned; everything else is fully rewritten)
    hipMemsetAsync(counts, 0, NSCAN * sizeof(int), stream);

    int n8 = n_feat / 8;   // 800000
    convert_bf16<<<(n8 + 255) / 256, 256, 0, stream>>>(h_src, hsb, n8);

    int nbE4 = ((n_edges + 3) / 4 + 255) / 256;
    edge_hist<<<nbE4, 256, 0, stream>>>(dst, counts, rank, n_edges);
    scan_block<<<NB_SCAN, SCAN_BS, 0, stream>>>(counts, offsets, partials);
    scan_add<<<NB_SCAN, SCAN_BS, 0, stream>>>(offsets, partials);
    edge_fill<<<nbE4, 256, 0, stream>>>(src, dst, rank, offsets, edge_src, n_edges);

    sage_fused<<<(N_NODES_C + 31) / 32, 256, 0, stream>>>(
        hsb, h_dst, offsets, edge_src, weight, bias, out, N_NODES_C);
}

// Round 6
// 200.053 us; speedup vs baseline: 1.4063x; 1.4063x over previous
//
#include <hip/hip_runtime.h>
#include <hip/hip_bf16.h>

#define N_NODES_C 100000
#define NSCAN     102400      // N padded to 25 * 4096 for the scan
#define SCAN_BS   1024        // threads per scan block (4 elems each -> 4096/block)
#define NB_SCAN   (NSCAN / (SCAN_BS * 4))   // 25 blocks

// ---------------------------------------------------------------------------
// bf16 helpers (packed 2 per uint, little-endian: low ushort = even element)
// ---------------------------------------------------------------------------
__device__ __forceinline__ float bflo(unsigned u) { return __uint_as_float(u << 16); }
__device__ __forceinline__ float bfhi(unsigned u) { return __uint_as_float(u & 0xffff0000u); }
__device__ __forceinline__ unsigned pack2(float f0, float f1)
{
    unsigned u0 = __float_as_uint(f0); u0 = (u0 + 0x7fffu + ((u0 >> 16) & 1u)) >> 16;
    unsigned u1 = __float_as_uint(f1); u1 = (u1 + 0x7fffu + ((u1 >> 16) & 1u)) >> 16;
    return u0 | (u1 << 16);
}

struct F8 { float v[8]; };
__device__ __forceinline__ void acc8(F8& a, uint4 u)
{
    a.v[0] += bflo(u.x); a.v[1] += bfhi(u.x);
    a.v[2] += bflo(u.y); a.v[3] += bfhi(u.y);
    a.v[4] += bflo(u.z); a.v[5] += bfhi(u.z);
    a.v[6] += bflo(u.w); a.v[7] += bfhi(u.w);
}

// h_src f32 -> packed bf16 copy (8 floats per thread)
__global__ __launch_bounds__(256) void convert_bf16(
    const float* __restrict__ x, uint4* __restrict__ y, int n8)
{
    int i = blockIdx.x * 256 + threadIdx.x;
    if (i >= n8) return;
    const float4* x4 = reinterpret_cast<const float4*>(x);
    float4 a = x4[i * 2 + 0];
    float4 b = x4[i * 2 + 1];
    uint4 o;
    o.x = pack2(a.x, a.y);
    o.y = pack2(a.z, a.w);
    o.z = pack2(b.x, b.y);
    o.w = pack2(b.z, b.w);
    y[i] = o;
}

// ---------------------------------------------------------------------------
// CSR build: histogram(+rank) -> block scan -> scan_add(inline partials) -> fill
// ---------------------------------------------------------------------------
__global__ __launch_bounds__(256) void edge_hist(
    const int* __restrict__ dst, int* __restrict__ counts,
    int* __restrict__ rank, int n_edges)
{
    int i = blockIdx.x * 256 + threadIdx.x;
    int b4 = i * 4;
    if (b4 + 3 < n_edges) {
        int4 d = reinterpret_cast<const int4*>(dst)[i];
        int4 rk;
        rk.x = atomicAdd(&counts[d.x], 1);
        rk.y = atomicAdd(&counts[d.y], 1);
        rk.z = atomicAdd(&counts[d.z], 1);
        rk.w = atomicAdd(&counts[d.w], 1);
        reinterpret_cast<int4*>(rank)[i] = rk;
    } else {
        for (int e = b4; e < n_edges; ++e)
            rank[e] = atomicAdd(&counts[dst[e]], 1);
    }
}

__global__ __launch_bounds__(SCAN_BS) void scan_block(
    const int* __restrict__ counts, int* __restrict__ offsets,
    int* __restrict__ partials)
{
    __shared__ int sd[2][SCAN_BS];
    int t = threadIdx.x, b = blockIdx.x;
    int4 c = reinterpret_cast<const int4*>(counts)[b * SCAN_BS + t];
    int tot = c.x + c.y + c.z + c.w;
    sd[0][t] = tot;
    __syncthreads();
    int pin = 0;
    #pragma unroll
    for (int off = 1; off < SCAN_BS; off <<= 1) {
        int v = sd[pin][t];
        if (t >= off) v += sd[pin][t - off];
        sd[pin ^ 1][t] = v;
        pin ^= 1;
        __syncthreads();
    }
    int incl = sd[pin][t];      // inclusive scan of per-thread sums
    int excl = incl - tot;
    int4 o;
    o.x = excl;
    o.y = excl + c.x;
    o.z = excl + c.x + c.y;
    o.w = excl + c.x + c.y + c.z;
    reinterpret_cast<int4*>(offsets)[b * SCAN_BS + t] = o;
    if (t == SCAN_BS - 1) partials[b] = incl;
}

// one block per scan_block tile; thread 0 sums the (<=24) preceding partials
__global__ __launch_bounds__(SCAN_BS) void scan_add(
    int* __restrict__ offsets, const int* __restrict__ partials)
{
    __shared__ int base_s;
    int b = blockIdx.x;
    if (threadIdx.x == 0) {
        int s = 0;
        for (int i = 0; i < b; ++i) s += partials[i];
        base_s = s;
    }
    __syncthreads();
    int i = b * SCAN_BS + threadIdx.x;
    int4 v = reinterpret_cast<int4*>(offsets)[i];
    v.x += base_s; v.y += base_s; v.z += base_s; v.w += base_s;
    reinterpret_cast<int4*>(offsets)[i] = v;
}

__global__ __launch_bounds__(256) void edge_fill(
    const int* __restrict__ src, const int* __restrict__ dst,
    const int* __restrict__ rank, const int* __restrict__ offsets,
    int* __restrict__ edge_src, int n_edges)
{
    int i = blockIdx.x * 256 + threadIdx.x;
    int b4 = i * 4;
    if (b4 + 3 < n_edges) {
        int4 s  = reinterpret_cast<const int4*>(src)[i];
        int4 d  = reinterpret_cast<const int4*>(dst)[i];
        int4 rk = reinterpret_cast<const int4*>(rank)[i];
        edge_src[offsets[d.x] + rk.x] = s.x;
        edge_src[offsets[d.y] + rk.y] = s.y;
        edge_src[offsets[d.z] + rk.z] = s.z;
        edge_src[offsets[d.w] + rk.w] = s.w;
    } else {
        for (int e = b4; e < n_edges; ++e)
            edge_src[offsets[dst[e]] + rank[e]] = src[e];
    }
}

// ---------------------------------------------------------------------------
// Fused gather-mean + GEMM.
// Block: 256 threads, 64 nodes. LDS: X tile only (32KB, swizzled float4).
// Gather (R2 structure x bf16): 4 threads/node; per edge each lane loads
// 2 uint4 bf16 chunks (row = 8 uint4 over 4 lanes); 4-edge unroll ->
// 8 independent 16B loads in flight per lane, issued before any use.
// W streams from global in the GEMM loop (L1-resident, 16-lane dedup).
// ---------------------------------------------------------------------------
__global__ __launch_bounds__(256) void sage_fused(
    const uint4* __restrict__ hsb,      // packed bf16 h_src [N][8] uint4
    const float* __restrict__ h_dst,
    const int*   __restrict__ offsets,
    const int*   __restrict__ edge_src,
    const float* __restrict__ weight,   // [64][128] row-major
    const float* __restrict__ bias,     // [64]
    float*       __restrict__ out,      // [N][64]
    int n_nodes)
{
    __shared__ float4 x4[64 * 32];   // x4[r][c] at r*32 + ((c + r) & 31)

    const int t    = threadIdx.x;
    const int base = blockIdx.x * 64;

    // stage h_dst (cols 0..15): 4 float4 per thread
    #pragma unroll
    for (int q = 0; q < 4; ++q) {
        int idx = t + q * 256;        // 0..1023
        int r   = idx >> 4;
        int k4  = idx & 15;
        int g   = base + r;
        float4 xv = make_float4(0.f, 0.f, 0.f, 0.f);
        if (g < n_nodes)
            xv = reinterpret_cast<const float4*>(h_dst)[(size_t)g * 16 + k4];
        x4[r * 32 + ((k4 + r) & 31)] = xv;
    }

    // gather neighbor mean (cols 16..31): 4 threads/node, 4-edge unroll,
    // 8 concurrent gathers per lane
    {
        const int j = t & 3;          // uint4 chunk pair: j and j+4
        const int r = t >> 2;         // node within tile (0..63)
        const int g = base + r;
        F8 accA, accB;                // features [8j..8j+8) and [8(j+4)..8(j+4)+8)
        #pragma unroll
        for (int q = 0; q < 8; ++q) { accA.v[q] = 0.f; accB.v[q] = 0.f; }
        float invd = 0.f;
        if (g < n_nodes) {
            int e0 = offsets[g];
            int e1 = offsets[g + 1];
            int e  = e0;
            for (; e + 4 <= e1; e += 4) {
                int s0 = edge_src[e + 0];
                int s1 = edge_src[e + 1];
                int s2 = edge_src[e + 2];
                int s3 = edge_src[e + 3];
                // issue all 8 gathers before any use
                uint4 p0 = hsb[(size_t)s0 * 8 + j];
                uint4 p1 = hsb[(size_t)s1 * 8 + j];
                uint4 p2 = hsb[(size_t)s2 * 8 + j];
                uint4 p3 = hsb[(size_t)s3 * 8 + j];
                uint4 q0 = hsb[(size_t)s0 * 8 + j + 4];
                uint4 q1 = hsb[(size_t)s1 * 8 + j + 4];
                uint4 q2 = hsb[(size_t)s2 * 8 + j + 4];
                uint4 q3 = hsb[(size_t)s3 * 8 + j + 4];
                acc8(accA, p0); acc8(accA, p1); acc8(accA, p2); acc8(accA, p3);
                acc8(accB, q0); acc8(accB, q1); acc8(accB, q2); acc8(accB, q3);
            }
            for (; e < e1; ++e) {
                int s = edge_src[e];
                uint4 p = hsb[(size_t)s * 8 + j];
                uint4 q = hsb[(size_t)s * 8 + j + 4];
                acc8(accA, p);
                acc8(accB, q);
            }
            int degv = e1 - e0;
            invd = 1.0f / (float)(degv > 1 ? degv : 1);
        }
        // chunk j  -> float4 cols 16+2j, 17+2j ; chunk j+4 -> 24+2j, 25+2j
        float4 w0 = make_float4(accA.v[0] * invd, accA.v[1] * invd,
                                accA.v[2] * invd, accA.v[3] * invd);
        float4 w1 = make_float4(accA.v[4] * invd, accA.v[5] * invd,
                                accA.v[6] * invd, accA.v[7] * invd);
        float4 w2 = make_float4(accB.v[0] * invd, accB.v[1] * invd,
                                accB.v[2] * invd, accB.v[3] * invd);
        float4 w3 = make_float4(accB.v[4] * invd, accB.v[5] * invd,
                                accB.v[6] * invd, accB.v[7] * invd);
        x4[r * 32 + (((16 + 2 * j) + r) & 31)] = w0;
        x4[r * 32 + (((17 + 2 * j) + r) & 31)] = w1;
        x4[r * 32 + (((24 + 2 * j) + r) & 31)] = w2;
        x4[r * 32 + (((25 + 2 * j) + r) & 31)] = w3;
    }
    __syncthreads();

    // GEMM: thread tile = 4 nodes x 4 outs; W streamed from global (L1)
    const int m  = t & 15;    // out-group: o0 = 4m
    const int r0 = t >> 4;    // node base: rows r0 + 16*i
    const int o0 = m * 4;

    const float4* w4g = reinterpret_cast<const float4*>(weight);
    float4 bv = reinterpret_cast<const float4*>(bias)[m];

    float acc[4][4];
    #pragma unroll
    for (int i = 0; i < 4; ++i) {
        acc[i][0] = bv.x; acc[i][1] = bv.y; acc[i][2] = bv.z; acc[i][3] = bv.w;
    }

    #pragma unroll 4
    for (int k4 = 0; k4 < 32; ++k4) {
        float4 wv[4];
        #pragma unroll
        for (int jj = 0; jj < 4; ++jj)
            wv[jj] = w4g[(o0 + jj) * 32 + k4];
        #pragma unroll
        for (int i = 0; i < 4; ++i) {
            int r = r0 + 16 * i;
            float4 xv = x4[r * 32 + ((k4 + r) & 31)];
            #pragma unroll
            for (int jj = 0; jj < 4; ++jj) {
                acc[i][jj] += xv.x * wv[jj].x + xv.y * wv[jj].y
                            + xv.z * wv[jj].z + xv.w * wv[jj].w;
            }
        }
    }

    #pragma unroll
    for (int i = 0; i < 4; ++i) {
        int g = base + r0 + 16 * i;
        if (g < n_nodes) {
            float4 ov = make_float4(acc[i][0], acc[i][1], acc[i][2], acc[i][3]);
            reinterpret_cast<float4*>(out)[(size_t)g * 16 + m] = ov;
        }
    }
}

// ---------------------------------------------------------------------------
extern "C" void kernel_launch(void* const* d_in, const int* in_sizes, int n_in,
                              void* d_out, int out_size, void* d_ws, size_t ws_size,
                              hipStream_t stream)
{
    const float* h_src  = (const float*)d_in[0];
    const float* h_dst  = (const float*)d_in[1];
    const int*   src    = (const int*)d_in[2];
    const int*   dst    = (const int*)d_in[3];
    const float* weight = (const float*)d_in[4];
    const float* bias   = (const float*)d_in[5];
    float*       out    = (float*)d_out;

    const int n_edges = in_sizes[2];
    const int n_feat  = in_sizes[0];   // N*64 floats

    // workspace layout (ints); all vector bases 16B-aligned
    int*   counts   = (int*)d_ws;              // NSCAN
    int*   offsets  = counts   + NSCAN;        // NSCAN  (offsets[N] valid)
    int*   partials = offsets  + NSCAN;        // 64
    int*   rank     = partials + 64;           // n_edges
    int*   edge_src = rank     + n_edges;      // n_edges
    uint4* hsb      = (uint4*)(edge_src + n_edges);   // N*64 bf16 = N*8 uint4

    // zero the histogram (ws is poisoned; everything else is fully rewritten)
    hipMemsetAsync(counts, 0, NSCAN * sizeof(int), stream);

    int n8 = n_feat / 8;   // 800000
    convert_bf16<<<(n8 + 255) / 256, 256, 0, stream>>>(h_src, hsb, n8);

    int nbE4 = ((n_edges + 3) / 4 + 255) / 256;
    edge_hist<<<nbE4, 256, 0, stream>>>(dst, counts, rank, n_edges);
    scan_block<<<NB_SCAN, SCAN_BS, 0, stream>>>(counts, offsets, partials);
    scan_add<<<NB_SCAN, SCAN_BS, 0, stream>>>(offsets, partials);
    edge_fill<<<nbE4, 256, 0, stream>>>(src, dst, rank, offsets, edge_src, n_edges);

    sage_fused<<<(N_NODES_C + 63) / 64, 256, 0, stream>>>(
        hsb, h_dst, offsets, edge_src, weight, bias, out, N_NODES_C);
}